// Round 7
// baseline (804.473 us; speedup 1.0000x reference)
//
#include <hip/hip_runtime.h>
#include <hip/hip_bf16.h>
#include <math.h>

#define T_DIM 2048
#define K_DIM 17
#define HID   64
#define B_DIM 32

typedef short s16x8 __attribute__((ext_vector_type(8)));
typedef short s16x4 __attribute__((ext_vector_type(4)));
typedef unsigned u32x2 __attribute__((ext_vector_type(2)));
typedef float f32x4 __attribute__((ext_vector_type(4)));

__device__ __forceinline__ float bf2f(short u) {
    unsigned v = ((unsigned)(unsigned short)u) << 16;
    return __builtin_bit_cast(float, v);
}
__device__ __forceinline__ short f2bf(float f) {          // cold path
    __hip_bfloat16 h = __float2bfloat16(f);
    return __builtin_bit_cast(short, h);
}
__device__ __forceinline__ unsigned pk2bf(float lo, float hi) {
    unsigned ul = __builtin_bit_cast(unsigned, lo);
    unsigned uh = __builtin_bit_cast(unsigned, hi);
    return ((ul + 0x8000u) >> 16) | ((uh + 0x8000u) & 0xFFFF0000u);
}

// COCO skeleton sparsity: column-v nonzeros of adj (incl. self).
__device__ const int d_NBR_PTR[18] = {0,3,6,9,11,13,17,21,24,27,29,31,34,37,40,43,45,47};
__device__ const int d_NBR_K[47] = {
    0,1,2,  0,1,3,  0,2,4,  1,3,  2,4,
    5,6,7,11,  5,6,8,12,  5,7,9,  6,8,10,  7,9,  8,10,
    5,11,13,  6,12,14,  11,13,15,  12,14,16,  13,15,  14,16 };
static constexpr int NBR_PTR[18] = {0,3,6,9,11,13,17,21,24,27,29,31,34,37,40,43,45,47};
static constexpr int NBR_K[47] = {
    0,1,2,  0,1,3,  0,2,4,  1,3,  2,4,
    5,6,7,11,  5,6,8,12,  5,7,9,  6,8,10,  7,9,  8,10,
    5,11,13,  6,12,14,  11,13,15,  12,14,16,  13,15,  14,16 };

// ---------------------------------------------------------------------------
// Fold GCN channel-mix into temporal conv weights (bf16).
//   effT0[o][k32]  k = dt*8+cin (cin<3, dt<3), rest 0    (block1, K=32)
//   effT12[blk][o][dt*64+c]                              (blocks 2,3, K=192)
//   bnc[blk*64+o] = s/sqrt(v+eps);  bnc[192+blk*64+o] = b - m*inv
// ---------------------------------------------------------------------------
__global__ void fold_weights_kernel(
    const float* __restrict__ gw0, const float* __restrict__ gw1,
    const float* __restrict__ gw2, const float* __restrict__ tcn,
    const float* __restrict__ bns, const float* __restrict__ bnb,
    const float* __restrict__ bnm, const float* __restrict__ bnv,
    short* __restrict__ effT0, short* __restrict__ effT12,
    float* __restrict__ bnc)
{
    int tid = blockIdx.x * blockDim.x + threadIdx.x;
    int stride = gridDim.x * blockDim.x;
    for (int idx = tid; idx < 2048; idx += stride) {
        int o = idx >> 5, k = idx & 31, dt = k >> 3, cin = k & 7;
        float s = 0.f;
        if (dt < 3 && cin < 3)
            for (int m = 0; m < 64; m++)
                s += gw0[cin * 64 + m] * tcn[(o * 64 + m) * 3 + dt];
        effT0[idx] = f2bf(s);
    }
    for (int idx = tid; idx < 24576; idx += stride) {
        int blk = idx / 12288;
        int r = idx - blk * 12288;
        int o = r / 192, k = r - o * 192, dt = k >> 6, c = k & 63;
        const float* gw = blk ? gw2 : gw1;
        const float* tw = tcn + (size_t)(blk + 1) * 64 * 64 * 3;
        float s = 0.f;
        for (int m = 0; m < 64; m++)
            s += gw[c * 64 + m] * tw[(o * 64 + m) * 3 + dt];
        effT12[idx] = f2bf(s);
    }
    for (int i = tid; i < 192; i += stride) {
        float inv = bns[i] * rsqrtf(bnv[i] + 1e-5f);
        bnc[i] = inv;
        bnc[192 + i] = bnb[i] - bnm[i] * inv;
    }
}

// ---------------------------------------------------------------------------
// Kernel A: blocks 1+2 fused, TT=4 output t's per WG, writes y2 to global.
// Slots: x span 8 t (u=t-(t0-2)); y1 span 6 t (s=t-(t0-1)); y2 out 4 t.
// MFMA: A = weights [m=o][k] in regs, B = activations from LDS.
// LDS ~32 KB -> 4-5 WG/CU; __launch_bounds__(256,4) caps VGPR at 128.
// ---------------------------------------------------------------------------
__global__ __launch_bounds__(256, 4) void stgcn_ab_kernel(
    const float* __restrict__ x, const float* __restrict__ adj,
    const short* __restrict__ effT0, const short* __restrict__ effT12,
    const float* __restrict__ bnc, short* __restrict__ y2)
{
    __shared__ float adj_s[289];
    __shared__ __align__(16) float xt[8 * 51];          // 1632 B
    __shared__ __align__(16) short xgA[102 * 72];       // 14688 B (alias xg1st 102*40)
    __shared__ __align__(16) short yb[102 * 72];        // 14688 B

    short* xg1st = xgA;

    const int tid = threadIdx.x;
    const int b = blockIdx.y;
    const int t0 = blockIdx.x * 4;
    const int lane = tid & 63;
    const int wave = tid >> 6;
    const int col = lane & 15;
    const int kgrp = lane >> 4;

    for (int i = tid; i < 289; i += 256) adj_s[i] = adj[i];
    {
        const int tbase = t0 - 2;
        const float* xb = x + (size_t)(b * T_DIM + tbase) * 51;
        for (int i = tid; i < 408; i += 256) {
            int tt = tbase + i / 51;
            xt[i] = (tt >= 0 && tt < T_DIM) ? xb[i] : 0.f;
        }
    }
    // A-frags (weights) for GEMM1
    s16x8 af1[4];
    #pragma unroll
    for (int mt = 0; mt < 4; mt++)
        af1[mt] = *(const s16x8*)(effT0 + (mt * 16 + col) * 32 + kgrp * 8);
    __syncthreads();

    // ---- gc1: x-tile -> xg1st rows (s2,j), K=32 layout; 102 rows ----
    if (tid < 102) {
        int s2 = tid / 17, j = tid - s2 * 17;
        float a9[9];
        #pragma unroll
        for (int q = 0; q < 9; q++) a9[q] = 0.f;
        int p0 = d_NBR_PTR[j], p1 = d_NBR_PTR[j + 1];
        for (int e = p0; e < p1; e++) {
            int k = d_NBR_K[e];
            float w = adj_s[k * 17 + j];
            #pragma unroll
            for (int dt = 0; dt < 3; dt++) {
                const float* xp = &xt[(s2 + dt) * 51 + k * 3];
                a9[dt * 3 + 0] += w * xp[0];
                a9[dt * 3 + 1] += w * xp[1];
                a9[dt * 3 + 2] += w * xp[2];
            }
        }
        __align__(16) unsigned ov[16];
        #pragma unroll
        for (int q = 0; q < 16; q++) ov[q] = 0u;
        #pragma unroll
        for (int dt = 0; dt < 3; dt++) {
            ov[dt * 4 + 0] = pk2bf(a9[dt * 3 + 0], a9[dt * 3 + 1]);
            ov[dt * 4 + 1] = pk2bf(a9[dt * 3 + 2], 0.f);
        }
        #pragma unroll
        for (int q = 0; q < 4; q++)
            *(int4*)&xg1st[tid * 40 + q * 8] = ((const int4*)ov)[q];
    }
    __syncthreads();

    // ---- GEMM1: rows 102 (7 tiles), K=32 -> y1 in yb ----
    {
        f32x4 inv4[4], sh4[4];
        #pragma unroll
        for (int mt = 0; mt < 4; mt++) {
            inv4[mt] = *(const f32x4*)&bnc[mt * 16 + kgrp * 4];
            sh4[mt]  = *(const f32x4*)&bnc[192 + mt * 16 + kgrp * 4];
        }
        for (int tile = wave; tile < 7; tile += 4) {
            const int r = tile * 16 + col;
            const int me = r < 102 ? r : 101;
            s16x8 bfr = *(const s16x8*)&xg1st[me * 40 + kgrp * 8];
            f32x4 acc[4];
            #pragma unroll
            for (int mt = 0; mt < 4; mt++)
                acc[mt] = __builtin_amdgcn_mfma_f32_16x16x32_bf16(
                    af1[mt], bfr, (f32x4){0.f, 0.f, 0.f, 0.f}, 0, 0, 0);
            const int s = me / 17;
            const int t = t0 - 1 + s;
            const bool rowok = (r < 102);
            const bool valid = rowok && (t >= 0) && (t < T_DIM);
            #pragma unroll
            for (int mt = 0; mt < 4; mt++) {
                float v0 = valid ? fmaxf(acc[mt][0] * inv4[mt][0] + sh4[mt][0], 0.f) : 0.f;
                float v1 = valid ? fmaxf(acc[mt][1] * inv4[mt][1] + sh4[mt][1], 0.f) : 0.f;
                float v2 = valid ? fmaxf(acc[mt][2] * inv4[mt][2] + sh4[mt][2], 0.f) : 0.f;
                float v3 = valid ? fmaxf(acc[mt][3] * inv4[mt][3] + sh4[mt][3], 0.f) : 0.f;
                u32x2 st; st[0] = pk2bf(v0, v1); st[1] = pk2bf(v2, v3);
                if (rowok)
                    *(u32x2*)&yb[r * 72 + mt * 16 + kgrp * 4] = st;
            }
        }
    }
    __syncthreads();

    // ---- gc2: y1 -> xgA (2 channels/thread, 192 threads) ----
    if (tid < 192) {
        const int s2 = tid >> 5, cp = tid & 31;
        float y0[17], y1r[17];
        #pragma unroll
        for (int k = 0; k < 17; k++) {
            unsigned u = *(const unsigned*)&yb[(s2 * 17 + k) * 72 + cp * 2];
            y0[k]  = bf2f((short)(u & 0xFFFF));
            y1r[k] = bf2f((short)(u >> 16));
        }
        #pragma unroll
        for (int v = 0; v < 17; v++) {
            float g0 = 0.f, g1 = 0.f;
            #pragma unroll
            for (int e = NBR_PTR[v]; e < NBR_PTR[v + 1]; e++) {
                int k = NBR_K[e];
                float w = adj_s[k * 17 + v];
                g0 += w * y0[k]; g1 += w * y1r[k];
            }
            *(unsigned*)&xgA[(s2 * 17 + v) * 72 + cp * 2] = pk2bf(g0, g1);
        }
    }
    // A-frags (weights) for GEMM2
    s16x8 af2[6][4];
    #pragma unroll
    for (int kk = 0; kk < 6; kk++)
        #pragma unroll
        for (int mt = 0; mt < 4; mt++)
            af2[kk][mt] = *(const s16x8*)(effT12 +
                (mt * 16 + col) * 192 + kk * 32 + kgrp * 8);
    __syncthreads();

    // ---- GEMM2: rows 68 (5 tiles), K=192 -> y2 global ----
    {
        f32x4 inv4[4], sh4[4];
        #pragma unroll
        for (int mt = 0; mt < 4; mt++) {
            inv4[mt] = *(const f32x4*)&bnc[64 + mt * 16 + kgrp * 4];
            sh4[mt]  = *(const f32x4*)&bnc[256 + mt * 16 + kgrp * 4];
        }
        const size_t gbase = ((size_t)(b * T_DIM + t0) * K_DIM) * 64;
        for (int tile = wave; tile < 5; tile += 4) {
            const int r = tile * 16 + col;
            const int me = r < 68 ? r : 67;
            f32x4 acc[4];
            #pragma unroll
            for (int mt = 0; mt < 4; mt++) acc[mt] = (f32x4){0.f, 0.f, 0.f, 0.f};
            #pragma unroll
            for (int kk = 0; kk < 6; kk++) {
                s16x8 bfr = *(const s16x8*)&xgA[
                    (me + 17 * (kk >> 1)) * 72 + (kk & 1) * 32 + kgrp * 8];
                #pragma unroll
                for (int mt = 0; mt < 4; mt++)
                    acc[mt] = __builtin_amdgcn_mfma_f32_16x16x32_bf16(
                        af2[kk][mt], bfr, acc[mt], 0, 0, 0);
            }
            const bool rowok = (r < 68);
            #pragma unroll
            for (int mt = 0; mt < 4; mt++) {
                s16x4 res = *(const s16x4*)&yb[(me + 17) * 72 + mt * 16 + kgrp * 4];
                float v0 = fmaxf(acc[mt][0] * inv4[mt][0] + sh4[mt][0], 0.f) + bf2f(res[0]);
                float v1 = fmaxf(acc[mt][1] * inv4[mt][1] + sh4[mt][1], 0.f) + bf2f(res[1]);
                float v2 = fmaxf(acc[mt][2] * inv4[mt][2] + sh4[mt][2], 0.f) + bf2f(res[2]);
                float v3 = fmaxf(acc[mt][3] * inv4[mt][3] + sh4[mt][3], 0.f) + bf2f(res[3]);
                u32x2 st; st[0] = pk2bf(v0, v1); st[1] = pk2bf(v2, v3);
                if (rowok)
                    *(u32x2*)&y2[gbase + (size_t)r * 64 + mt * 16 + kgrp * 4] = st;
            }
        }
    }
}

// ---------------------------------------------------------------------------
// Kernel B: block 3 (DIL=2) + pool, TT=8 output t's per WG.
// gc3 gathers y2 from global (L3-hot, coalesced 128 B rows) -> LDS;
// GEMM3 + BN/ReLU + global residual + (t,v)-pool -> part[b][bx][64].
// ---------------------------------------------------------------------------
__global__ __launch_bounds__(256, 4) void stgcn_c_kernel(
    const short* __restrict__ y2, const float* __restrict__ adj,
    const short* __restrict__ effW3, const float* __restrict__ bnc,
    float* __restrict__ part, int b0)
{
    __shared__ float adj_s[289];
    __shared__ __align__(16) short xgA[204 * 72];   // 29376 B
    __shared__ float pr[4][64];

    const int tid = threadIdx.x;
    const int b = blockIdx.y;
    const int t0 = blockIdx.x * 8;
    const int lane = tid & 63;
    const int wave = tid >> 6;
    const int col = lane & 15;
    const int kgrp = lane >> 4;

    for (int i = tid; i < 289; i += 256) adj_s[i] = adj[i];
    s16x8 af3[6][4];
    #pragma unroll
    for (int kk = 0; kk < 6; kk++)
        #pragma unroll
        for (int mt = 0; mt < 4; mt++)
            af3[kk][mt] = *(const s16x8*)(effW3 +
                (mt * 16 + col) * 192 + kk * 32 + kgrp * 8);
    __syncthreads();

    // ---- gc3: y2 (global) -> xgA rows (u,v), u in [0,12) ----
    for (int it = tid; it < 384; it += 256) {
        const int u = it >> 5, cp = it & 31;
        const int tp = t0 - 2 + u;
        float y0[17], y1r[17];
        if (tp >= 0 && tp < T_DIM) {
            const short* yp = y2 + ((size_t)(b * T_DIM + tp) * K_DIM) * 64 + cp * 2;
            #pragma unroll
            for (int k = 0; k < 17; k++) {
                unsigned w = *(const unsigned*)&yp[k * 64];
                y0[k]  = bf2f((short)(w & 0xFFFF));
                y1r[k] = bf2f((short)(w >> 16));
            }
        } else {
            #pragma unroll
            for (int k = 0; k < 17; k++) { y0[k] = 0.f; y1r[k] = 0.f; }
        }
        #pragma unroll
        for (int v = 0; v < 17; v++) {
            float g0 = 0.f, g1 = 0.f;
            #pragma unroll
            for (int e = NBR_PTR[v]; e < NBR_PTR[v + 1]; e++) {
                int k = NBR_K[e];
                float w = adj_s[k * 17 + v];
                g0 += w * y0[k]; g1 += w * y1r[k];
            }
            *(unsigned*)&xgA[(u * 17 + v) * 72 + cp * 2] = pk2bf(g0, g1);
        }
    }
    __syncthreads();

    // ---- GEMM3: rows 136 (9 tiles), K=192, DIL=2, + pool ----
    f32x4 psum[4];
    #pragma unroll
    for (int mt = 0; mt < 4; mt++) psum[mt] = (f32x4){0.f, 0.f, 0.f, 0.f};
    {
        f32x4 inv4[4], sh4[4];
        #pragma unroll
        for (int mt = 0; mt < 4; mt++) {
            inv4[mt] = *(const f32x4*)&bnc[128 + mt * 16 + kgrp * 4];
            sh4[mt]  = *(const f32x4*)&bnc[320 + mt * 16 + kgrp * 4];
        }
        const size_t gbase = ((size_t)(b * T_DIM + t0) * K_DIM) * 64;
        for (int tile = wave; tile < 9; tile += 4) {
            const int r = tile * 16 + col;
            const int me = r < 136 ? r : 135;
            f32x4 acc[4];
            #pragma unroll
            for (int mt = 0; mt < 4; mt++) acc[mt] = (f32x4){0.f, 0.f, 0.f, 0.f};
            #pragma unroll
            for (int kk = 0; kk < 6; kk++) {
                s16x8 bfr = *(const s16x8*)&xgA[
                    (me + 34 * (kk >> 1)) * 72 + (kk & 1) * 32 + kgrp * 8];
                #pragma unroll
                for (int mt = 0; mt < 4; mt++)
                    acc[mt] = __builtin_amdgcn_mfma_f32_16x16x32_bf16(
                        af3[kk][mt], bfr, acc[mt], 0, 0, 0);
            }
            const bool rowok = (r < 136);
            #pragma unroll
            for (int mt = 0; mt < 4; mt++) {
                s16x4 res = *(const s16x4*)&y2[gbase + (size_t)me * 64 + mt * 16 + kgrp * 4];
                if (rowok) {
                    psum[mt][0] += fmaxf(acc[mt][0] * inv4[mt][0] + sh4[mt][0], 0.f) + bf2f(res[0]);
                    psum[mt][1] += fmaxf(acc[mt][1] * inv4[mt][1] + sh4[mt][1], 0.f) + bf2f(res[1]);
                    psum[mt][2] += fmaxf(acc[mt][2] * inv4[mt][2] + sh4[mt][2], 0.f) + bf2f(res[2]);
                    psum[mt][3] += fmaxf(acc[mt][3] * inv4[mt][3] + sh4[mt][3], 0.f) + bf2f(res[3]);
                }
            }
        }
    }
    // pool: reduce over the 16 n-columns (low 4 lane bits)
    #pragma unroll
    for (int off = 1; off <= 8; off <<= 1)
        #pragma unroll
        for (int mt = 0; mt < 4; mt++) {
            psum[mt][0] += __shfl_xor(psum[mt][0], off);
            psum[mt][1] += __shfl_xor(psum[mt][1], off);
            psum[mt][2] += __shfl_xor(psum[mt][2], off);
            psum[mt][3] += __shfl_xor(psum[mt][3], off);
        }
    if (col == 0)
        #pragma unroll
        for (int mt = 0; mt < 4; mt++)
            *(f32x4*)&pr[wave][mt * 16 + kgrp * 4] = psum[mt];
    __syncthreads();
    if (tid < 64)
        part[((size_t)(b0 + b) * 256 + blockIdx.x) * 64 + tid] =
            pr[0][tid] + pr[1][tid] + pr[2][tid] + pr[3][tid];
}

// ---------------------------------------------------------------------------
// Sum 256 partials per (b,c), mean, LayerNorm, FC. 1 wave per b.
// ---------------------------------------------------------------------------
__global__ __launch_bounds__(64) void finish_kernel(
    const float* __restrict__ part, const float* __restrict__ ln_s,
    const float* __restrict__ ln_b, const float* __restrict__ fc_w,
    const float* __restrict__ fc_b, float* __restrict__ out)
{
    const int b = blockIdx.x;
    const int c = threadIdx.x;
    float s = 0.f;
    for (int i = 0; i < 256; i++)
        s += part[((size_t)b * 256 + i) * 64 + c];
    float feat = s / (float)(T_DIM * K_DIM);

    float m = feat;
    #pragma unroll
    for (int off = 32; off > 0; off >>= 1) m += __shfl_down(m, off);
    m = __shfl(m, 0) / 64.f;
    float d = feat - m;
    float v = d * d;
    #pragma unroll
    for (int off = 32; off > 0; off >>= 1) v += __shfl_down(v, off);
    v = __shfl(v, 0) / 64.f;
    float norm = d * rsqrtf(v + 1e-5f) * ln_s[c] + ln_b[c];

    __shared__ float ns[64];
    ns[c] = norm;
    __syncthreads();
    if (c < 10) {
        float o = fc_b[c];
        for (int i = 0; i < 64; i++) o += ns[i] * fc_w[i * 10 + c];
        out[b * 10 + c] = o;
    }
}

// ---------------------------------------------------------------------------
extern "C" void kernel_launch(void* const* d_in, const int* in_sizes, int n_in,
                              void* d_out, int out_size, void* d_ws, size_t ws_size,
                              hipStream_t stream)
{
    const float* kpts = (const float*)d_in[0];
    const float* adj  = (const float*)d_in[1];
    const float* gw0  = (const float*)d_in[2];
    const float* gw1  = (const float*)d_in[3];
    const float* gw2  = (const float*)d_in[4];
    const float* tcn  = (const float*)d_in[5];
    const float* bns  = (const float*)d_in[6];
    const float* bnb  = (const float*)d_in[7];
    const float* bnm  = (const float*)d_in[8];
    const float* bnv  = (const float*)d_in[9];
    const float* lns  = (const float*)d_in[10];
    const float* lnb  = (const float*)d_in[11];
    const float* fcw  = (const float*)d_in[12];
    const float* fcb  = (const float*)d_in[13];
    float* out = (float*)d_out;

    // ws: bnc(384 f) | part(32*256*64 f) | effT0(2048 s) | effT12(24576 s) | y2
    float* bnc  = (float*)d_ws;
    float* part = bnc + 384;
    short* effT0  = (short*)(part + (size_t)B_DIM * 256 * 64);
    short* effT12 = effT0 + 2048;
    short* y2     = effT12 + 24576;
    const size_t fixed_bytes = 384 * 4 + (size_t)B_DIM * 256 * 64 * 4
                             + 2048 * 2 + 24576 * 2;          // ~2.15 MB
    const size_t y2_per_b = (size_t)T_DIM * K_DIM * 64 * 2;   // 4,456,448 B

    int cb = B_DIM;
    while (cb > 1 && fixed_bytes + (size_t)cb * y2_per_b > ws_size) cb >>= 1;

    fold_weights_kernel<<<64, 256, 0, stream>>>(gw0, gw1, gw2, tcn,
                                                bns, bnb, bnm, bnv,
                                                effT0, effT12, bnc);

    for (int b0 = 0; b0 < B_DIM; b0 += cb) {
        stgcn_ab_kernel<<<dim3(T_DIM / 4, cb), 256, 0, stream>>>(
            kpts + (size_t)b0 * T_DIM * K_DIM * 3, adj, effT0, effT12, bnc, y2);
        stgcn_c_kernel<<<dim3(T_DIM / 8, cb), 256, 0, stream>>>(
            y2, adj, effT12 + 12288, bnc, part, b0);
    }

    finish_kernel<<<B_DIM, 64, 0, stream>>>(part, lns, lnb, fcw, fcb, out);
}

// Round 8
// 371.465 us; speedup vs baseline: 2.1657x; 2.1657x over previous
//
#include <hip/hip_runtime.h>
#include <hip/hip_bf16.h>
#include <math.h>

#define T_DIM 2048
#define K_DIM 17
#define HID   64
#define B_DIM 32

typedef short s16x8 __attribute__((ext_vector_type(8)));
typedef short s16x4 __attribute__((ext_vector_type(4)));
typedef unsigned u32x2 __attribute__((ext_vector_type(2)));
typedef float f32x4 __attribute__((ext_vector_type(4)));

__device__ __forceinline__ float bf2f(short u) {
    unsigned v = ((unsigned)(unsigned short)u) << 16;
    return __builtin_bit_cast(float, v);
}
__device__ __forceinline__ short f2bf(float f) {          // cold path
    __hip_bfloat16 h = __float2bfloat16(f);
    return __builtin_bit_cast(short, h);
}
__device__ __forceinline__ unsigned pk2bf(float lo, float hi) {
    unsigned ul = __builtin_bit_cast(unsigned, lo);
    unsigned uh = __builtin_bit_cast(unsigned, hi);
    return ((ul + 0x8000u) >> 16) | ((uh + 0x8000u) & 0xFFFF0000u);
}

// COCO skeleton sparsity: column-v nonzeros of adj (incl. self).
__device__ const int d_NBR_PTR[18] = {0,3,6,9,11,13,17,21,24,27,29,31,34,37,40,43,45,47};
__device__ const int d_NBR_K[47] = {
    0,1,2,  0,1,3,  0,2,4,  1,3,  2,4,
    5,6,7,11,  5,6,8,12,  5,7,9,  6,8,10,  7,9,  8,10,
    5,11,13,  6,12,14,  11,13,15,  12,14,16,  13,15,  14,16 };
static constexpr int NBR_PTR[18] = {0,3,6,9,11,13,17,21,24,27,29,31,34,37,40,43,45,47};
static constexpr int NBR_K[47] = {
    0,1,2,  0,1,3,  0,2,4,  1,3,  2,4,
    5,6,7,11,  5,6,8,12,  5,7,9,  6,8,10,  7,9,  8,10,
    5,11,13,  6,12,14,  11,13,15,  12,14,16,  13,15,  14,16 };

// ---------------------------------------------------------------------------
// Fold GCN channel-mix into temporal conv weights (bf16).
//   effT0[o][k32]  k = dt*8+cin (cin<3, dt<3), rest 0    (block1, K=32)
//   effT12[blk][o][dt*64+c]                              (blocks 2,3, K=192)
//   bnc[blk*64+o] = s/sqrt(v+eps);  bnc[192+blk*64+o] = b - m*inv
// ---------------------------------------------------------------------------
__global__ void fold_weights_kernel(
    const float* __restrict__ gw0, const float* __restrict__ gw1,
    const float* __restrict__ gw2, const float* __restrict__ tcn,
    const float* __restrict__ bns, const float* __restrict__ bnb,
    const float* __restrict__ bnm, const float* __restrict__ bnv,
    short* __restrict__ effT0, short* __restrict__ effT12,
    float* __restrict__ bnc)
{
    int tid = blockIdx.x * blockDim.x + threadIdx.x;
    int stride = gridDim.x * blockDim.x;
    for (int idx = tid; idx < 2048; idx += stride) {
        int o = idx >> 5, k = idx & 31, dt = k >> 3, cin = k & 7;
        float s = 0.f;
        if (dt < 3 && cin < 3)
            for (int m = 0; m < 64; m++)
                s += gw0[cin * 64 + m] * tcn[(o * 64 + m) * 3 + dt];
        effT0[idx] = f2bf(s);
    }
    for (int idx = tid; idx < 24576; idx += stride) {
        int blk = idx / 12288;
        int r = idx - blk * 12288;
        int o = r / 192, k = r - o * 192, dt = k >> 6, c = k & 63;
        const float* gw = blk ? gw2 : gw1;
        const float* tw = tcn + (size_t)(blk + 1) * 64 * 64 * 3;
        float s = 0.f;
        for (int m = 0; m < 64; m++)
            s += gw[c * 64 + m] * tw[(o * 64 + m) * 3 + dt];
        effT12[idx] = f2bf(s);
    }
    for (int i = tid; i < 192; i += stride) {
        float inv = bns[i] * rsqrtf(bnv[i] + 1e-5f);
        bnc[i] = inv;
        bnc[192 + i] = bnb[i] - bnm[i] * inv;
    }
}

// ---------------------------------------------------------------------------
// Kernel 1: block1 as K=32 MFMA GEMM. TT=16 output t's per WG.
// gc1 from LDS x-tile -> xg1st (272 rows x 40 sh), GEMM -> y1 global.
// Out index is linear in MFMA row r: (t0+s)*17+j = t0*17 + r.
// LDS ~26.6 KB; __launch_bounds__(256,5) -> VGPR<=102, 5 WG/CU.
// ---------------------------------------------------------------------------
__global__ __launch_bounds__(256, 5) void stgcn_b1_kernel(
    const float* __restrict__ x, const float* __restrict__ adj,
    const short* __restrict__ effT0, const float* __restrict__ bnc,
    short* __restrict__ y1)
{
    __shared__ float adj_s[289];
    __shared__ __align__(16) float xt[18 * 51];          // 3672 B
    __shared__ __align__(16) short xg1st[272 * 40];      // 21760 B

    const int tid = threadIdx.x;
    const int b = blockIdx.y;
    const int t0 = blockIdx.x * 16;
    const int lane = tid & 63;
    const int wave = tid >> 6;
    const int col = lane & 15;
    const int kgrp = lane >> 4;

    for (int i = tid; i < 289; i += 256) adj_s[i] = adj[i];
    {
        const int tbase = t0 - 1;
        const float* xb = x + (size_t)(b * T_DIM + tbase) * 51;
        for (int i = tid; i < 918; i += 256) {
            int tt = tbase + i / 51;
            xt[i] = (tt >= 0 && tt < T_DIM) ? xb[i] : 0.f;
        }
    }
    s16x8 af1[4];
    #pragma unroll
    for (int mt = 0; mt < 4; mt++)
        af1[mt] = *(const s16x8*)(effT0 + (mt * 16 + col) * 32 + kgrp * 8);
    __syncthreads();

    // gc1: row p=(s,j), output t=t0+s, stages dt=0..2 from xt rows s+dt
    for (int p = tid; p < 272; p += 256) {
        int s = p / 17, j = p - s * 17;
        float a9[9];
        #pragma unroll
        for (int q = 0; q < 9; q++) a9[q] = 0.f;
        int p0 = d_NBR_PTR[j], p1 = d_NBR_PTR[j + 1];
        for (int e = p0; e < p1; e++) {
            int k = d_NBR_K[e];
            float w = adj_s[k * 17 + j];
            #pragma unroll
            for (int dt = 0; dt < 3; dt++) {
                const float* xp = &xt[(s + dt) * 51 + k * 3];
                a9[dt * 3 + 0] += w * xp[0];
                a9[dt * 3 + 1] += w * xp[1];
                a9[dt * 3 + 2] += w * xp[2];
            }
        }
        __align__(16) unsigned ov[16];
        #pragma unroll
        for (int q = 0; q < 16; q++) ov[q] = 0u;
        #pragma unroll
        for (int dt = 0; dt < 3; dt++) {
            ov[dt * 4 + 0] = pk2bf(a9[dt * 3 + 0], a9[dt * 3 + 1]);
            ov[dt * 4 + 1] = pk2bf(a9[dt * 3 + 2], 0.f);
        }
        #pragma unroll
        for (int q = 0; q < 4; q++)
            *(int4*)&xg1st[p * 40 + q * 8] = ((const int4*)ov)[q];
    }
    __syncthreads();

    // GEMM1: 17 tiles of 16 rows (exact), K=32
    f32x4 inv4[4], sh4[4];
    #pragma unroll
    for (int mt = 0; mt < 4; mt++) {
        inv4[mt] = *(const f32x4*)&bnc[mt * 16 + kgrp * 4];
        sh4[mt]  = *(const f32x4*)&bnc[192 + mt * 16 + kgrp * 4];
    }
    const size_t gbase = ((size_t)b * T_DIM + t0) * K_DIM * 64;
    for (int tile = wave; tile < 17; tile += 4) {
        const int r = tile * 16 + col;
        s16x8 bfr = *(const s16x8*)&xg1st[r * 40 + kgrp * 8];
        f32x4 acc[4];
        #pragma unroll
        for (int mt = 0; mt < 4; mt++)
            acc[mt] = __builtin_amdgcn_mfma_f32_16x16x32_bf16(
                af1[mt], bfr, (f32x4){0.f, 0.f, 0.f, 0.f}, 0, 0, 0);
        #pragma unroll
        for (int mt = 0; mt < 4; mt++) {
            float v0 = fmaxf(acc[mt][0] * inv4[mt][0] + sh4[mt][0], 0.f);
            float v1 = fmaxf(acc[mt][1] * inv4[mt][1] + sh4[mt][1], 0.f);
            float v2 = fmaxf(acc[mt][2] * inv4[mt][2] + sh4[mt][2], 0.f);
            float v3 = fmaxf(acc[mt][3] * inv4[mt][3] + sh4[mt][3], 0.f);
            u32x2 st; st[0] = pk2bf(v0, v1); st[1] = pk2bf(v2, v3);
            *(u32x2*)&y1[gbase + (size_t)r * 64 + mt * 16 + kgrp * 4] = st;
        }
    }
}

// ---------------------------------------------------------------------------
// Kernels 2/3: K=192 MFMA GEMM with o-halved weight fragments (48 VGPR).
// TT=8 output t's per WG.  gc stages SPAN t's of yin (global, L3-hot) into
// xgA; GEMM reads B rows at r + 17*ROWSTEP... per k-chunk; epilogue does
// BN+ReLU+residual, then either stores yout (POOL=0) or pools (POOL=1).
// wave&1 = o-half, wave>>1 = tile parity.  launch_bounds(256,4): 4 WG/CU.
// ---------------------------------------------------------------------------
template<int DIL, bool POOL>
__global__ __launch_bounds__(256, 4) void stgcn_b23_kernel(
    const short* __restrict__ yin, const float* __restrict__ adj,
    const short* __restrict__ effW, const float* __restrict__ bnc, int blk,
    short* __restrict__ yout, float* __restrict__ part, int b0)
{
    constexpr int SPAN = 8 + 2 * DIL;                 // 10 or 12
    __shared__ float adj_s[289];
    __shared__ __align__(16) short xgA[SPAN * 17 * 72];  // 24480 / 29376 B
    __shared__ float pr[4][32];

    const int tid = threadIdx.x;
    const int b = blockIdx.y;
    const int t0 = blockIdx.x * 8;
    const int lane = tid & 63;
    const int wave = tid >> 6;
    const int col = lane & 15;
    const int kgrp = lane >> 4;
    const int h = wave & 1;                           // o-half

    for (int i = tid; i < 289; i += 256) adj_s[i] = adj[i];
    __syncthreads();

    // gc: SPAN*16 threads, each (u, cq) handles 4 channels for 17 v's
    if (tid < SPAN * 16) {
        const int u = tid >> 4, cq = tid & 15;
        const int tp = t0 - DIL + u;
        float yv[17][4];
        if (tp >= 0 && tp < T_DIM) {
            const short* yp = yin + ((size_t)(b * T_DIM + tp) * K_DIM) * 64 + cq * 4;
            #pragma unroll
            for (int k = 0; k < 17; k++) {
                s16x4 w = *(const s16x4*)&yp[k * 64];
                yv[k][0] = bf2f(w[0]); yv[k][1] = bf2f(w[1]);
                yv[k][2] = bf2f(w[2]); yv[k][3] = bf2f(w[3]);
            }
        } else {
            #pragma unroll
            for (int k = 0; k < 17; k++)
                { yv[k][0] = 0.f; yv[k][1] = 0.f; yv[k][2] = 0.f; yv[k][3] = 0.f; }
        }
        #pragma unroll
        for (int v = 0; v < 17; v++) {
            float g0 = 0.f, g1 = 0.f, g2 = 0.f, g3 = 0.f;
            #pragma unroll
            for (int e = NBR_PTR[v]; e < NBR_PTR[v + 1]; e++) {
                int k = NBR_K[e];
                float w = adj_s[k * 17 + v];
                g0 += w * yv[k][0]; g1 += w * yv[k][1];
                g2 += w * yv[k][2]; g3 += w * yv[k][3];
            }
            u32x2 st; st[0] = pk2bf(g0, g1); st[1] = pk2bf(g2, g3);
            *(u32x2*)&xgA[(u * 17 + v) * 72 + cq * 4] = st;
        }
    }

    // o-halved weight fragments: 48 VGPR
    s16x8 af[6][2];
    #pragma unroll
    for (int kk = 0; kk < 6; kk++)
        #pragma unroll
        for (int m = 0; m < 2; m++)
            af[kk][m] = *(const s16x8*)(effW +
                (h * 32 + m * 16 + col) * 192 + kk * 32 + kgrp * 8);
    f32x4 inv4[2], sh4[2];
    #pragma unroll
    for (int m = 0; m < 2; m++) {
        inv4[m] = *(const f32x4*)&bnc[blk * 64 + h * 32 + m * 16 + kgrp * 4];
        sh4[m]  = *(const f32x4*)&bnc[192 + blk * 64 + h * 32 + m * 16 + kgrp * 4];
    }
    __syncthreads();

    // GEMM: 136 out rows -> 9 tiles; wave-pair splits tiles, h splits o
    const size_t gbase = ((size_t)b * T_DIM + t0) * K_DIM * 64;
    f32x4 psum[2];
    psum[0] = (f32x4){0.f, 0.f, 0.f, 0.f};
    psum[1] = (f32x4){0.f, 0.f, 0.f, 0.f};

    for (int tile = (wave >> 1); tile < 9; tile += 2) {
        const int r = tile * 16 + col;
        const int me = r < 136 ? r : 135;
        f32x4 acc[2];
        acc[0] = (f32x4){0.f, 0.f, 0.f, 0.f};
        acc[1] = (f32x4){0.f, 0.f, 0.f, 0.f};
        #pragma unroll
        for (int kk = 0; kk < 6; kk++) {
            s16x8 bfr = *(const s16x8*)&xgA[
                (me + 17 * DIL * (kk >> 1)) * 72 + (kk & 1) * 32 + kgrp * 8];
            #pragma unroll
            for (int m = 0; m < 2; m++)
                acc[m] = __builtin_amdgcn_mfma_f32_16x16x32_bf16(
                    af[kk][m], bfr, acc[m], 0, 0, 0);
        }
        const bool rowok = (r < 136);
        #pragma unroll
        for (int m = 0; m < 2; m++) {
            const size_t yi = gbase + (size_t)me * 64 + h * 32 + m * 16 + kgrp * 4;
            s16x4 res = *(const s16x4*)&yin[yi];
            float v0 = fmaxf(acc[m][0] * inv4[m][0] + sh4[m][0], 0.f) + bf2f(res[0]);
            float v1 = fmaxf(acc[m][1] * inv4[m][1] + sh4[m][1], 0.f) + bf2f(res[1]);
            float v2 = fmaxf(acc[m][2] * inv4[m][2] + sh4[m][2], 0.f) + bf2f(res[2]);
            float v3 = fmaxf(acc[m][3] * inv4[m][3] + sh4[m][3], 0.f) + bf2f(res[3]);
            if (POOL) {
                if (rowok) {
                    psum[m][0] += v0; psum[m][1] += v1;
                    psum[m][2] += v2; psum[m][3] += v3;
                }
            } else {
                u32x2 st; st[0] = pk2bf(v0, v1); st[1] = pk2bf(v2, v3);
                if (rowok) *(u32x2*)&yout[yi] = st;
            }
        }
    }

    if (POOL) {
        #pragma unroll
        for (int off = 1; off <= 8; off <<= 1)
            #pragma unroll
            for (int m = 0; m < 2; m++) {
                psum[m][0] += __shfl_xor(psum[m][0], off);
                psum[m][1] += __shfl_xor(psum[m][1], off);
                psum[m][2] += __shfl_xor(psum[m][2], off);
                psum[m][3] += __shfl_xor(psum[m][3], off);
            }
        if (col == 0) {
            #pragma unroll
            for (int m = 0; m < 2; m++)
                *(f32x4*)&pr[wave][m * 16 + kgrp * 4] = psum[m];
        }
        __syncthreads();
        if (tid < 64) {
            int hh = tid >> 5, idx = tid & 31;
            part[((size_t)(b0 + b) * 256 + blockIdx.x) * 64 + tid] =
                pr[hh][idx] + pr[hh + 2][idx];
        }
    }
}

// ---------------------------------------------------------------------------
// Sum 256 partials per (b,c), mean, LayerNorm, FC. 1 wave per b.
// ---------------------------------------------------------------------------
__global__ __launch_bounds__(64) void finish_kernel(
    const float* __restrict__ part, const float* __restrict__ ln_s,
    const float* __restrict__ ln_b, const float* __restrict__ fc_w,
    const float* __restrict__ fc_b, float* __restrict__ out)
{
    const int b = blockIdx.x;
    const int c = threadIdx.x;
    float s = 0.f;
    for (int i = 0; i < 256; i++)
        s += part[((size_t)b * 256 + i) * 64 + c];
    float feat = s / (float)(T_DIM * K_DIM);

    float m = feat;
    #pragma unroll
    for (int off = 32; off > 0; off >>= 1) m += __shfl_down(m, off);
    m = __shfl(m, 0) / 64.f;
    float d = feat - m;
    float v = d * d;
    #pragma unroll
    for (int off = 32; off > 0; off >>= 1) v += __shfl_down(v, off);
    v = __shfl(v, 0) / 64.f;
    float norm = d * rsqrtf(v + 1e-5f) * ln_s[c] + ln_b[c];

    __shared__ float ns[64];
    ns[c] = norm;
    __syncthreads();
    if (c < 10) {
        float o = fc_b[c];
        for (int i = 0; i < 64; i++) o += ns[i] * fc_w[i * 10 + c];
        out[b * 10 + c] = o;
    }
}

// ---------------------------------------------------------------------------
extern "C" void kernel_launch(void* const* d_in, const int* in_sizes, int n_in,
                              void* d_out, int out_size, void* d_ws, size_t ws_size,
                              hipStream_t stream)
{
    const float* kpts = (const float*)d_in[0];
    const float* adj  = (const float*)d_in[1];
    const float* gw0  = (const float*)d_in[2];
    const float* gw1  = (const float*)d_in[3];
    const float* gw2  = (const float*)d_in[4];
    const float* tcn  = (const float*)d_in[5];
    const float* bns  = (const float*)d_in[6];
    const float* bnb  = (const float*)d_in[7];
    const float* bnm  = (const float*)d_in[8];
    const float* bnv  = (const float*)d_in[9];
    const float* lns  = (const float*)d_in[10];
    const float* lnb  = (const float*)d_in[11];
    const float* fcw  = (const float*)d_in[12];
    const float* fcb  = (const float*)d_in[13];
    float* out = (float*)d_out;

    // ws: bnc(384 f) | part(32*256*64 f) | effT0(2048 s) | effT12(24576 s) | y1 | y2
    float* bnc  = (float*)d_ws;
    float* part = bnc + 384;
    short* effT0  = (short*)(part + (size_t)B_DIM * 256 * 64);
    short* effT12 = effT0 + 2048;
    short* y1     = effT12 + 24576;
    const size_t fixed_bytes = 384 * 4 + (size_t)B_DIM * 256 * 64 * 4
                             + 2048 * 2 + 24576 * 2;          // ~2.15 MB
    const size_t y_per_b = (size_t)T_DIM * K_DIM * 64 * 2;    // 4,456,448 B

    int cb = B_DIM;
    while (cb > 1 && fixed_bytes + 2 * (size_t)cb * y_per_b > ws_size) cb >>= 1;
    short* y2 = y1 + (size_t)cb * T_DIM * K_DIM * 64;

    fold_weights_kernel<<<64, 256, 0, stream>>>(gw0, gw1, gw2, tcn,
                                                bns, bnb, bnm, bnv,
                                                effT0, effT12, bnc);

    for (int b0 = 0; b0 < B_DIM; b0 += cb) {
        stgcn_b1_kernel<<<dim3(T_DIM / 16, cb), 256, 0, stream>>>(
            kpts + (size_t)b0 * T_DIM * K_DIM * 3, adj, effT0, bnc, y1);
        stgcn_b23_kernel<1, false><<<dim3(T_DIM / 8, cb), 256, 0, stream>>>(
            y1, adj, effT12, bnc, 1, y2, nullptr, 0);
        stgcn_b23_kernel<2, true><<<dim3(T_DIM / 8, cb), 256, 0, stream>>>(
            y2, adj, effT12 + 12288, bnc, 2, nullptr, part, b0);
    }

    finish_kernel<<<B_DIM, 64, 0, stream>>>(part, lns, lnb, fcw, fcb, out);
}